// Round 4
// baseline (8356.062 us; speedup 1.0000x reference)
//
#include <hip/hip_runtime.h>

#define N_NODES 200000
#define N_EDGES 6400000
#define HID 200
#define NPB 32        // nodes per block in mlp
#define ASTRF 201     // fp32 activation row stride (conflict-free for m-parallel reads)

typedef unsigned short u16;
typedef unsigned int u32;

// Module-scope scratch (R3 showed d_ws vs globals makes no difference; keep globals).
__device__ __align__(16) float g_agg[N_NODES];
__device__ __align__(16) float g_wf[6 * HID * HID];  // hidden weights, fp32, [l][k][f]
__device__ int g_isbf;                               // 1 = float buffers are bf16-packed

__device__ __forceinline__ float bf2f(u16 u) {
  union { u32 i; float f; } v; v.i = ((u32)u) << 16; return v.f;
}
__device__ __forceinline__ u16 f2bf(float f) {  // round-to-nearest-even
  u32 i = __float_as_uint(f);
  return (u16)((i + 0x7FFFu + ((i >> 16) & 1u)) >> 16);
}
__device__ __forceinline__ float ldf(const void* p, int i, int isbf) {
  return isbf ? bf2f(((const u16*)p)[i]) : ((const float*)p)[i];
}

// ---- K0: dtype sniff on x ----
// bf16-packed: low 16 bits of each u32 word are a bf16 of N(0,1) -> exponent
// field ((w>>7)&0xFF) in [110,135] for ~64/64 words. fp32: those bits are
// mid-mantissa, ~uniform -> ~6/64 hits. Threshold 48 separates by >15 sigma.
__global__ void sniff_kernel(const u32* __restrict__ xw) {
  if (threadIdx.x == 0 && blockIdx.x == 0) {
    int cnt = 0;
    for (int i = 0; i < 64; ++i) {
      u32 e = (xw[i] >> 7) & 0xFFu;
      cnt += (e >= 110u && e <= 135u) ? 1 : 0;
    }
    g_isbf = (cnt >= 48) ? 1 : 0;
  }
}

// ---- K1: zero agg + convert hidden weights to fp32 ----
__global__ void prep_kernel(const void* __restrict__ w_hid) {
  int t = blockIdx.x * blockDim.x + threadIdx.x;
  int isbf = g_isbf;
  if (t < N_NODES) g_agg[t] = 0.f;
  if (t < 6 * HID * HID) g_wf[t] = ldf(w_hid, t, isbf);
}

// ---- K2: edge scatter-add (int32 or int64 indices; bf16 or fp32 x) ----
__global__ void scatter_kernel(const int* __restrict__ ei, const void* __restrict__ x) {
  int t = blockIdx.x * blockDim.x + threadIdx.x;  // 4 edges each
  int e = t * 4;
  int isbf = g_isbf;
  bool is64 = ((ei[1] | ei[3] | ei[5] | ei[7]) == 0);
  int s0, s1, s2, s3, d0, d1, d2, d3;
  if (is64) {
    int4 a = *(const int4*)(ei + 2 * e);
    int4 b = *(const int4*)(ei + 2 * e + 4);
    int4 c = *(const int4*)(ei + 2 * N_EDGES + 2 * e);
    int4 d = *(const int4*)(ei + 2 * N_EDGES + 2 * e + 4);
    s0 = a.x; s1 = a.z; s2 = b.x; s3 = b.z;
    d0 = c.x; d1 = c.z; d2 = d.x; d3 = d.z;
  } else {
    int4 s4 = *(const int4*)(ei + e);
    int4 d4 = *(const int4*)(ei + N_EDGES + e);
    s0 = s4.x; s1 = s4.y; s2 = s4.z; s3 = s4.w;
    d0 = d4.x; d1 = d4.y; d2 = d4.z; d3 = d4.w;
  }
  atomicAdd(&g_agg[d0], ldf(x, s0, isbf));
  atomicAdd(&g_agg[d1], ldf(x, s1, isbf));
  atomicAdd(&g_agg[d2], ldf(x, s2, isbf));
  atomicAdd(&g_agg[d3], ldf(x, s3, isbf));
}

// ---- K3: fused GraphConv + 8-layer MLP + sigmoid, pure fp32 VALU (bisect) ----
__global__ __launch_bounds__(256) void mlp_kernel(
    const void* __restrict__ x,
    const void* __restrict__ w_rel, const void* __restrict__ b_rel, const void* __restrict__ w_root,
    const void* __restrict__ w_in, const void* __restrict__ b_in,
    const void* __restrict__ b_hid, const void* __restrict__ w_out, const void* __restrict__ b_out,
    void* __restrict__ out) {
  __shared__ float actA[NPB][ASTRF];
  __shared__ float actB[NPB][ASTRF];
  __shared__ float h0s[NPB];

  const int tid = threadIdx.x;
  const int nb = blockIdx.x * NPB;
  const int isbf = g_isbf;

  // GraphConv: h0 = agg*w_rel + b_rel + x*w_root
  if (tid < NPB) {
    int node = nb + tid;
    h0s[tid] = g_agg[node] * ldf(w_rel, 0, isbf) + ldf(b_rel, 0, isbf) +
               ldf(x, node, isbf) * ldf(w_root, 0, isbf);
  }
  __syncthreads();

  // Input layer: h1[m][f] = relu(h0[m]*w_in[f] + b_in[f])
  for (int i = tid; i < NPB * HID; i += 256) {
    int mm = i / HID, ff = i - mm * HID;
    float v = h0s[mm] * ldf(w_in, ff, isbf) + ldf(b_in, ff, isbf);
    actA[mm][ff] = v > 0.f ? v : 0.f;
  }
  __syncthreads();

  // 6 hidden layers: thread (m = tid>>3, c = tid&7) computes 25 features of node m
  const int m = tid >> 3, c = tid & 7;
  float(*ain)[ASTRF] = actA;
  float(*aout)[ASTRF] = actB;
  for (int l = 0; l < 6; ++l) {
    float acc[25];
#pragma unroll
    for (int j = 0; j < 25; ++j) acc[j] = ldf(b_hid, l * HID + c * 25 + j, isbf);
    const float* wl = g_wf + l * HID * HID + c * 25;
    for (int k = 0; k < HID; ++k) {
      float a = ain[m][k];
      const float* wr = wl + k * HID;
#pragma unroll
      for (int j = 0; j < 25; ++j) acc[j] = fmaf(a, wr[j], acc[j]);
    }
#pragma unroll
    for (int j = 0; j < 25; ++j) {
      float v = acc[j];
      aout[m][c * 25 + j] = v > 0.f ? v : 0.f;
    }
    float(*tsw)[ASTRF] = ain; ain = aout; aout = tsw;
    __syncthreads();
  }

  // Output layer: logit[m] = sum_f h6[m][f]*w_out[f] + b_out; sigmoid
  float s = 0.f;
#pragma unroll
  for (int j = 0; j < 25; ++j) s += ain[m][c * 25 + j] * ldf(w_out, c * 25 + j, isbf);
  s += __shfl_down(s, 4);
  s += __shfl_down(s, 2);
  s += __shfl_down(s, 1);
  if (c == 0) {
    float logit = s + ldf(b_out, 0, isbf);
    float o = 1.f / (1.f + __expf(-logit));
    int node = nb + m;
    if (isbf) ((u16*)out)[node] = f2bf(o);
    else ((float*)out)[node] = o;
  }
}

extern "C" void kernel_launch(void* const* d_in, const int* in_sizes, int n_in,
                              void* d_out, int out_size, void* d_ws, size_t ws_size,
                              hipStream_t stream) {
  const void* x      = d_in[0];
  const int* ei      = (const int*)d_in[1];
  const void* w_rel  = d_in[2];
  const void* b_rel  = d_in[3];
  const void* w_root = d_in[4];
  const void* w_in   = d_in[5];
  const void* b_in   = d_in[6];
  const void* w_hid  = d_in[7];
  const void* b_hid  = d_in[8];
  const void* w_out  = d_in[9];
  const void* b_out  = d_in[10];
  (void)d_ws; (void)ws_size; (void)in_sizes; (void)n_in; (void)out_size;

  sniff_kernel<<<1, 64, 0, stream>>>((const u32*)x);
  prep_kernel<<<(6 * HID * HID + 255) / 256, 256, 0, stream>>>(w_hid);
  scatter_kernel<<<N_EDGES / 4 / 256, 256, 0, stream>>>(ei, x);
  mlp_kernel<<<N_NODES / NPB, 256, 0, stream>>>(
      x, w_rel, b_rel, w_root, w_in, b_in, b_hid, w_out, b_out, d_out);
}

// Round 5
// 1699.918 us; speedup vs baseline: 4.9156x; 4.9156x over previous
//
#include <hip/hip_runtime.h>

#define N_NODES 200000
#define N_EDGES 6400000
#define HID 200
#define NPB 32                    // nodes per block
#define ASTR 232                  // activation row stride (bf16 elems)
#define APLANE (NPB * ASTR)       // 7424 elems = 14848 B per plane
#define WSTR 232                  // weight k-stride
#define WROWS 224                 // padded N
#define WELEMS (WROWS * WSTR)     // 51968 elems = 103936 B
#define WCHUNK (WELEMS / 8)       // 6496 16-B chunks

typedef float f32x4 __attribute__((ext_vector_type(4)));
typedef short s16x8 __attribute__((ext_vector_type(8)));
typedef unsigned short u16;
typedef unsigned int u32;

__device__ __align__(16) float g_agg[N_NODES];
__device__ __align__(16) float g_wf[6 * HID * HID];   // fp32 [l][k][f] (VALU fallback)
__device__ __align__(16) u16 g_wp[6 * WELEMS];        // bf16 W^T padded [l][n][k] (MFMA)
__device__ int g_isbf;

__device__ __forceinline__ float bf2f(u16 u) {
  union { u32 i; float f; } v; v.i = ((u32)u) << 16; return v.f;
}
__device__ __forceinline__ u16 f2bf(float f) {  // RNE
  u32 i = __float_as_uint(f);
  return (u16)((i + 0x7FFFu + ((i >> 16) & 1u)) >> 16);
}
__device__ __forceinline__ float ldf(const void* p, int i, int isbf) {
  return isbf ? bf2f(((const u16*)p)[i]) : ((const float*)p)[i];
}
__device__ __forceinline__ u16 ldbf(const void* p, int i, int isbf) {
  return isbf ? ((const u16*)p)[i] : f2bf(((const float*)p)[i]);
}
__device__ __forceinline__ void load_lds16(const void* g, void* l) {
  __builtin_amdgcn_global_load_lds(
      (const __attribute__((address_space(1))) u32*)g,
      (__attribute__((address_space(3))) u32*)l, 16, 0, 0);
}

// ---- K0: dtype sniff (validated in R4) ----
__global__ void sniff_kernel(const u32* __restrict__ xw) {
  if (threadIdx.x == 0 && blockIdx.x == 0) {
    int cnt = 0;
    for (int i = 0; i < 64; ++i) {
      u32 e = (xw[i] >> 7) & 0xFFu;
      cnt += (e >= 110u && e <= 135u) ? 1 : 0;
    }
    g_isbf = (cnt >= 48) ? 1 : 0;
  }
}

// ---- K1: zero agg + both weight forms ----
__global__ void prep_kernel(const void* __restrict__ w_hid) {
  int t = blockIdx.x * blockDim.x + threadIdx.x;
  int isbf = g_isbf;
  if (t < N_NODES) g_agg[t] = 0.f;
  if (t < 6 * HID * HID) g_wf[t] = ldf(w_hid, t, isbf);
  if (t < 6 * WELEMS) {
    int l = t / WELEMS;
    int r = t - l * WELEMS;
    int n = r / WSTR;
    int k = r - n * WSTR;
    u16 v = 0;
    if (n < HID && k < HID) v = ldbf(w_hid, (l * HID + k) * HID + n, isbf);
    g_wp[t] = v;
  }
}

// ---- K2: edge scatter-add (validated in R4) ----
__global__ void scatter_kernel(const int* __restrict__ ei, const void* __restrict__ x) {
  int t = blockIdx.x * blockDim.x + threadIdx.x;
  int e = t * 4;
  int isbf = g_isbf;
  bool is64 = ((ei[1] | ei[3] | ei[5] | ei[7]) == 0);
  int s0, s1, s2, s3, d0, d1, d2, d3;
  if (is64) {
    int4 a = *(const int4*)(ei + 2 * e);
    int4 b = *(const int4*)(ei + 2 * e + 4);
    int4 c = *(const int4*)(ei + 2 * N_EDGES + 2 * e);
    int4 d = *(const int4*)(ei + 2 * N_EDGES + 2 * e + 4);
    s0 = a.x; s1 = a.z; s2 = b.x; s3 = b.z;
    d0 = c.x; d1 = c.z; d2 = d.x; d3 = d.z;
  } else {
    int4 s4 = *(const int4*)(ei + e);
    int4 d4 = *(const int4*)(ei + N_EDGES + e);
    s0 = s4.x; s1 = s4.y; s2 = s4.z; s3 = s4.w;
    d0 = d4.x; d1 = d4.y; d2 = d4.z; d3 = d4.w;
  }
  atomicAdd(&g_agg[d0], ldf(x, s0, isbf));
  atomicAdd(&g_agg[d1], ldf(x, s1, isbf));
  atomicAdd(&g_agg[d2], ldf(x, s2, isbf));
  atomicAdd(&g_agg[d3], ldf(x, s3, isbf));
}

// ---- K3: fused MLP. MFMA path with in-kernel self-test; VALU fallback. ----
__global__ __launch_bounds__(256, 1) void mlp_kernel(
    const void* __restrict__ x,
    const void* __restrict__ w_rel, const void* __restrict__ b_rel, const void* __restrict__ w_root,
    const void* __restrict__ w_in, const void* __restrict__ b_in,
    const void* __restrict__ b_hid, const void* __restrict__ w_out, const void* __restrict__ b_out,
    void* __restrict__ out) {
  extern __shared__ char smem[];
  u16* hiA = (u16*)smem;                                   // 4 act planes, 14848 B each
  u16* loA = hiA + APLANE;
  u16* hiB = loA + APLANE;
  u16* loB = hiB + APLANE;
  u16* wlds = loB + APLANE;                                // 103936 B
  float* h0s = (float*)(smem + 4 * APLANE * 2 + WELEMS * 2);  // offset 163328, 128 B
  int* smodep = (int*)(smem + 163456);                        // 4 B  (total 163460)

  const int tid = threadIdx.x;
  const int nb = blockIdx.x * NPB;
  const int isbf = g_isbf;
  const int lane = tid & 63;
  const int wv = tid >> 6;
  const int l15 = lane & 15;
  const int q = lane >> 4;

  // --- MFMA self-test (wave 1): exact integer-valued product, checked against
  // per-lane scalar truth under claimed and transposed D layouts. ---
  if (wv == 1) {
    s16x8 av, bv;
#pragma unroll
    for (int j = 0; j < 8; ++j) {
      int k = q * 8 + j;                      // same fragment k-map as hot loop
      int a = ((l15 * 31 + k * 7) % 13) - 6;
      int b = ((l15 * 17 + k * 5) % 11) - 5;
      av[j] = f2bf((float)a);
      bv[j] = f2bf((float)b);
    }
    f32x4 d = __builtin_amdgcn_mfma_f32_16x16x32_bf16(av, bv, (f32x4){0.f, 0.f, 0.f, 0.f}, 0, 0, 0);
    bool ok0 = true, ok1 = true;
#pragma unroll
    for (int r = 0; r < 4; ++r) {
      int mr = q * 4 + r;
      int t0 = 0, t1 = 0;
      for (int k = 0; k < 32; ++k) {
        t0 += (((mr * 31 + k * 7) % 13) - 6) * (((l15 * 17 + k * 5) % 11) - 5);
        t1 += (((l15 * 31 + k * 7) % 13) - 6) * (((mr * 17 + k * 5) % 11) - 5);
      }
      ok0 = ok0 && (d[r] == (float)t0);
      ok1 = ok1 && (d[r] == (float)t1);
    }
    int mode = __all(ok0) ? 0 : (__all(ok1) ? 1 : 2);
    if (lane == 0) *smodep = mode;
  }

  // --- GraphConv h0 (wave 0) ---
  if (tid < NPB) {
    int node = nb + tid;
    h0s[tid] = g_agg[node] * ldf(w_rel, 0, isbf) + ldf(b_rel, 0, isbf) +
               ldf(x, node, isbf) * ldf(w_root, 0, isbf);
  }
  __syncthreads();
  const int mode = *smodep;

  if (mode < 2) {
    // ================= MFMA path =================
    // Input layer -> hi/lo planes (v = hi + lo, fp32-equivalent precision)
    for (int idx = tid; idx < APLANE; idx += 256) {
      int m = idx / ASTR, j = idx - m * ASTR;
      float v = 0.f;
      if (j < HID) {
        v = h0s[m] * ldf(w_in, j, isbf) + ldf(b_in, j, isbf);
        v = fmaxf(v, 0.f);
      }
      u16 h = f2bf(v);
      hiA[idx] = h;
      loA[idx] = f2bf(v - bf2f(h));
    }

    const int mh = (wv >> 1) * 16;      // row tile: 0 or 16
    const int ct = (wv & 1) * 7;        // col tiles: 0..6 or 7..13
    u16* hIn = hiA; u16* lIn = loA; u16* hOut = hiB; u16* lOut = loB;

    for (int l = 0; l < 6; ++l) {
      __syncthreads();
      const u16* wg = g_wp + l * WELEMS;
      for (int c = tid; c < WCHUNK; c += 256) load_lds16(wg + c * 8, wlds + c * 8);
      __syncthreads();

      f32x4 acc[7];
#pragma unroll
      for (int n = 0; n < 7; ++n) acc[n] = (f32x4){0.f, 0.f, 0.f, 0.f};

      const u16* hp = hIn + (mh + l15) * ASTR + q * 8;
      const u16* lp = lIn + (mh + l15) * ASTR + q * 8;
      const u16* bp = wlds + (ct * 16 + l15) * WSTR + q * 8;
#pragma unroll
      for (int ks = 0; ks < 7; ++ks) {
        s16x8 ah = *(const s16x8*)(hp + ks * 32);
        s16x8 al = *(const s16x8*)(lp + ks * 32);
#pragma unroll
        for (int n = 0; n < 7; ++n) {
          s16x8 b = *(const s16x8*)(bp + n * 16 * WSTR + ks * 32);
          acc[n] = __builtin_amdgcn_mfma_f32_16x16x32_bf16(ah, b, acc[n], 0, 0, 0);
          acc[n] = __builtin_amdgcn_mfma_f32_16x16x32_bf16(al, b, acc[n], 0, 0, 0);
        }
      }

      // epilogue: bias + relu + hi/lo split; D layout per self-tested mode
#pragma unroll
      for (int n = 0; n < 7; ++n) {
        int ctile = (ct + n) * 16;
#pragma unroll
        for (int r = 0; r < 4; ++r) {
          int m_in = (mode == 0) ? (q * 4 + r) : l15;
          int n_in = (mode == 0) ? l15 : (q * 4 + r);
          int row = mh + m_in, col = ctile + n_in;
          float v = acc[n][r] + ((col < HID) ? ldf(b_hid, l * HID + col, isbf) : 0.f);
          v = fmaxf(v, 0.f);
          u16 h = f2bf(v);
          hOut[row * ASTR + col] = h;
          lOut[row * ASTR + col] = f2bf(v - bf2f(h));
        }
      }
      u16* t0 = hIn; hIn = hOut; hOut = t0;
      u16* t1 = lIn; lIn = lOut; lOut = t1;
    }

    __syncthreads();
    // Output layer
    {
      int m = tid >> 3, c = tid & 7;
      const u16* hr = hIn + m * ASTR;
      const u16* lr = lIn + m * ASTR;
      float s = 0.f;
      for (int j = c * 25; j < c * 25 + 25; ++j)
        s += (bf2f(hr[j]) + bf2f(lr[j])) * ldf(w_out, j, isbf);
      s += __shfl_down(s, 4);
      s += __shfl_down(s, 2);
      s += __shfl_down(s, 1);
      if (c == 0) {
        float logit = s + ldf(b_out, 0, isbf);
        float o = 1.f / (1.f + __expf(-logit));
        if (isbf) ((u16*)out)[nb + m] = f2bf(o);
        else ((float*)out)[nb + m] = o;
      }
    }
  } else {
    // ================= VALU fallback (R4-validated structure) =================
    float(*fA)[201] = (float(*)[201])smem;            // aliases act planes region
    float(*fB)[201] = (float(*)[201])(smem + NPB * 201 * 4);
    for (int i = tid; i < NPB * HID; i += 256) {
      int mm = i / HID, ff = i - mm * HID;
      float v = h0s[mm] * ldf(w_in, ff, isbf) + ldf(b_in, ff, isbf);
      fA[mm][ff] = v > 0.f ? v : 0.f;
    }
    __syncthreads();
    const int m = tid >> 3, c = tid & 7;
    float(*ain)[201] = fA;
    float(*aout)[201] = fB;
    for (int l = 0; l < 6; ++l) {
      float acc[25];
#pragma unroll
      for (int j = 0; j < 25; ++j) acc[j] = ldf(b_hid, l * HID + c * 25 + j, isbf);
      const float* wl = g_wf + l * HID * HID + c * 25;
      for (int k = 0; k < HID; ++k) {
        float a = ain[m][k];
        const float* wr = wl + k * HID;
#pragma unroll
        for (int j = 0; j < 25; ++j) acc[j] = fmaf(a, wr[j], acc[j]);
      }
#pragma unroll
      for (int j = 0; j < 25; ++j) {
        float v = acc[j];
        aout[m][c * 25 + j] = v > 0.f ? v : 0.f;
      }
      float(*tsw)[201] = ain; ain = aout; aout = tsw;
      __syncthreads();
    }
    float s = 0.f;
#pragma unroll
    for (int j = 0; j < 25; ++j) s += ain[m][c * 25 + j] * ldf(w_out, c * 25 + j, isbf);
    s += __shfl_down(s, 4);
    s += __shfl_down(s, 2);
    s += __shfl_down(s, 1);
    if (c == 0) {
      float logit = s + ldf(b_out, 0, isbf);
      float o = 1.f / (1.f + __expf(-logit));
      if (isbf) ((u16*)out)[nb + m] = f2bf(o);
      else ((float*)out)[nb + m] = o;
    }
  }
}

extern "C" void kernel_launch(void* const* d_in, const int* in_sizes, int n_in,
                              void* d_out, int out_size, void* d_ws, size_t ws_size,
                              hipStream_t stream) {
  const void* x      = d_in[0];
  const int* ei      = (const int*)d_in[1];
  const void* w_rel  = d_in[2];
  const void* b_rel  = d_in[3];
  const void* w_root = d_in[4];
  const void* w_in   = d_in[5];
  const void* b_in   = d_in[6];
  const void* w_hid  = d_in[7];
  const void* b_hid  = d_in[8];
  const void* w_out  = d_in[9];
  const void* b_out  = d_in[10];
  (void)d_ws; (void)ws_size; (void)in_sizes; (void)n_in; (void)out_size;

  sniff_kernel<<<1, 64, 0, stream>>>((const u32*)x);
  prep_kernel<<<(6 * WELEMS + 255) / 256, 256, 0, stream>>>(w_hid);
  scatter_kernel<<<N_EDGES / 4 / 256, 256, 0, stream>>>(ei, x);
  const int smem_bytes = 163460;  // 4 act planes + W tile + h0s + mode flag
  mlp_kernel<<<N_NODES / NPB, 256, smem_bytes, stream>>>(
      x, w_rel, b_rel, w_root, w_in, b_in, b_hid, w_out, b_out, d_out);
}

// Round 6
// 922.633 us; speedup vs baseline: 9.0568x; 1.8425x over previous
//
#include <hip/hip_runtime.h>

#define N_NODES 200000
#define N_EDGES 6400000
#define HID 200
#define NREP 4                    // scatter accumulator replicas
#define MT 64                     // nodes per block
#define ASTR 232                  // act row stride (elems): 464 B = 29*16 (aligned), 116 words mod 32 = 20 -> 2-way banks
#define APLANE (MT * ASTR)        // 14848 elems = 29696 B per plane
#define WSTR 232
#define WROWS 224
#define WELEMS (WROWS * WSTR)     // 51968 elems = 103936 B
#define WCHUNK (WELEMS / 8)       // 6496 16-B chunks

// LDS byte offsets: hi 0..29696, lo ..59392, wlds ..163328, h0s ..163584
#define LDS_LO 29696
#define LDS_W 59392
#define LDS_H0 163328
#define LDS_TOTAL 163584

typedef float f32x4 __attribute__((ext_vector_type(4)));
typedef short s16x8 __attribute__((ext_vector_type(8)));
typedef unsigned short u16;
typedef unsigned int u32;

__device__ __align__(16) float g_agg[NREP * N_NODES];
__device__ __align__(16) float g_wf[6 * HID * HID];   // fp32 [l][k][f] (VALU fallback)
__device__ __align__(16) u16 g_wp[6 * WELEMS];        // bf16 W^T padded [l][n][k] (MFMA)
__device__ int g_isbf;

__device__ __forceinline__ float bf2f(u16 u) {
  union { u32 i; float f; } v; v.i = ((u32)u) << 16; return v.f;
}
__device__ __forceinline__ u16 f2bf(float f) {  // RNE
  u32 i = __float_as_uint(f);
  return (u16)((i + 0x7FFFu + ((i >> 16) & 1u)) >> 16);
}
__device__ __forceinline__ float ldf(const void* p, int i, int isbf) {
  return isbf ? bf2f(((const u16*)p)[i]) : ((const float*)p)[i];
}
__device__ __forceinline__ u16 ldbf(const void* p, int i, int isbf) {
  return isbf ? ((const u16*)p)[i] : f2bf(((const float*)p)[i]);
}
__device__ __forceinline__ void load_lds16(const void* g, void* l) {
  __builtin_amdgcn_global_load_lds(
      (const __attribute__((address_space(1))) u32*)g,
      (__attribute__((address_space(3))) u32*)l, 16, 0, 0);
}

// ---- rank-2 MFMA layout self-test, reference folded at compile time ----
constexpr int tf1(int m) { return (m & 3) + 1; }
constexpr int tf2(int m) { return ((m >> 2) & 3) + 2; }
constexpr int tg1(int k) { return (k & 7) + 1; }
constexpr int tg2(int k) { return ((k >> 3) & 3) + 1; }
constexpr int tu1(int k) { return ((k * 3) & 7) + 1; }
constexpr int tu2(int k) { return ((k >> 2) & 3) + 2; }
constexpr int tw1(int n) { return ((n * 5) & 7) + 1; }
constexpr int tw2(int n) { return ((n >> 2) & 3) + 1; }
constexpr int calcS(int i, int j) {
  int s = 0;
  for (int k = 0; k < 32; ++k)
    s += (i ? tg2(k) : tg1(k)) * (j ? tu2(k) : tu1(k));
  return s;
}
__device__ __forceinline__ float refD(int m, int n) {
  constexpr int S11 = calcS(0, 0), S12 = calcS(0, 1), S21 = calcS(1, 0), S22 = calcS(1, 1);
  return (float)(tf1(m) * tw1(n) * S11 + tf1(m) * tw2(n) * S12 +
                 tf2(m) * tw1(n) * S21 + tf2(m) * tw2(n) * S22);
}
__device__ int mfma_selftest(int l15, int q) {
  s16x8 av, bv;
#pragma unroll
  for (int j = 0; j < 8; ++j) {
    int k = q * 8 + j;                 // exactly the hot loop's believed k-map
    av[j] = f2bf((float)(tf1(l15) * tg1(k) + tf2(l15) * tg2(k)));
    bv[j] = f2bf((float)(tu1(k) * tw1(l15) + tu2(k) * tw2(l15)));
  }
  f32x4 d = __builtin_amdgcn_mfma_f32_16x16x32_bf16(av, bv, (f32x4){0.f, 0.f, 0.f, 0.f}, 0, 0, 0);
  bool ok0 = true, ok1 = true;
#pragma unroll
  for (int r = 0; r < 4; ++r) {
    ok0 = ok0 && (d[r] == refD(q * 4 + r, l15));
    ok1 = ok1 && (d[r] == refD(l15, q * 4 + r));
  }
  return __all(ok0) ? 0 : (__all(ok1) ? 1 : 2);
}

// ---- K0: dtype sniff ----
__global__ void sniff_kernel(const u32* __restrict__ xw) {
  int i = threadIdx.x;  // 64 threads
  u32 e = (xw[i] >> 7) & 0xFFu;
  unsigned long long b = __ballot(e >= 110u && e <= 135u);
  if (i == 0) g_isbf = (__popcll(b) >= 48) ? 1 : 0;
}

// ---- K1: zero replicas + both weight forms ----
__global__ void prep_kernel(const void* __restrict__ w_hid) {
  int t = blockIdx.x * blockDim.x + threadIdx.x;
  int isbf = g_isbf;
  if (t < NREP * N_NODES) g_agg[t] = 0.f;
  if (t < 6 * HID * HID) g_wf[t] = ldf(w_hid, t, isbf);
  if (t < 6 * WELEMS) {
    int l = t / WELEMS;
    int r = t - l * WELEMS;
    int n = r / WSTR;
    int k = r - n * WSTR;
    u16 v = 0;
    if (n < HID && k < HID) v = ldbf(w_hid, (l * HID + k) * HID + n, isbf);
    g_wp[t] = v;
  }
}

// ---- K2: edge scatter-add into replica blockIdx&3 ----
__global__ void scatter_kernel(const int* __restrict__ ei, const void* __restrict__ x) {
  int t = blockIdx.x * blockDim.x + threadIdx.x;
  int e = t * 4;
  int isbf = g_isbf;
  float* agg = g_agg + (size_t)(blockIdx.x & (NREP - 1)) * N_NODES;
  bool is64 = ((ei[1] | ei[3] | ei[5] | ei[7]) == 0);
  int s0, s1, s2, s3, d0, d1, d2, d3;
  if (is64) {
    int4 a = *(const int4*)(ei + 2 * e);
    int4 b = *(const int4*)(ei + 2 * e + 4);
    int4 c = *(const int4*)(ei + 2 * N_EDGES + 2 * e);
    int4 d = *(const int4*)(ei + 2 * N_EDGES + 2 * e + 4);
    s0 = a.x; s1 = a.z; s2 = b.x; s3 = b.z;
    d0 = c.x; d1 = c.z; d2 = d.x; d3 = d.z;
  } else {
    int4 s4 = *(const int4*)(ei + e);
    int4 d4 = *(const int4*)(ei + N_EDGES + e);
    s0 = s4.x; s1 = s4.y; s2 = s4.z; s3 = s4.w;
    d0 = d4.x; d1 = d4.y; d2 = d4.z; d3 = d4.w;
  }
  atomicAdd(&agg[d0], ldf(x, s0, isbf));
  atomicAdd(&agg[d1], ldf(x, s1, isbf));
  atomicAdd(&agg[d2], ldf(x, s2, isbf));
  atomicAdd(&agg[d3], ldf(x, s3, isbf));
}

// ---- K3: fused MLP, 1024 threads / 16 waves, in-place hi/lo act planes ----
__global__ __launch_bounds__(1024) void mlp_kernel(
    const void* __restrict__ x,
    const void* __restrict__ w_rel, const void* __restrict__ b_rel, const void* __restrict__ w_root,
    const void* __restrict__ w_in, const void* __restrict__ b_in,
    const void* __restrict__ b_hid, const void* __restrict__ w_out, const void* __restrict__ b_out,
    void* __restrict__ out) {
  extern __shared__ char smem[];
  u16* hi = (u16*)smem;
  u16* lo = (u16*)(smem + LDS_LO);
  u16* wlds = (u16*)(smem + LDS_W);
  float* h0s = (float*)(smem + LDS_H0);

  const int tid = threadIdx.x;
  const int nb = blockIdx.x * MT;
  const int isbf = g_isbf;
  const int lane = tid & 63;
  const int wv = tid >> 6;
  const int l15 = lane & 15;
  const int q = lane >> 4;

  const int mode = mfma_selftest(l15, q);  // ~200 instrs, wave-uniform

  // GraphConv h0 (replica-summed)
  if (tid < MT) {
    int node = nb + tid;
    float a = g_agg[node] + g_agg[N_NODES + node] +
              g_agg[2 * N_NODES + node] + g_agg[3 * N_NODES + node];
    h0s[tid] = a * ldf(w_rel, 0, isbf) + ldf(b_rel, 0, isbf) +
               ldf(x, node, isbf) * ldf(w_root, 0, isbf);
  }
  __syncthreads();

  if (mode < 2) {
    // Input layer -> hi/lo planes (cols 200..231 zeroed; never rewritten)
    for (int idx = tid; idx < APLANE; idx += 1024) {
      int m = idx / ASTR, j = idx - m * ASTR;
      float v = 0.f;
      if (j < HID) {
        v = h0s[m] * ldf(w_in, j, isbf) + ldf(b_in, j, isbf);
        v = fmaxf(v, 0.f);
      }
      u16 h = f2bf(v);
      hi[idx] = h;
      lo[idx] = f2bf(v - bf2f(h));
    }

    const int band = wv >> 2;                    // 4 row-bands of 16
    const int g = wv & 3;                        // col groups: tiles 4/4/3/3
    const int ct0 = (g < 2) ? g * 4 : 8 + (g - 2) * 3;
    const int cnt = (g < 2) ? 4 : 3;

    for (int l = 0; l < 6; ++l) {
      __syncthreads();  // prev epilogue writes + prev wlds reads complete
      const u16* wg = g_wp + l * WELEMS;
      for (int c = tid; c < WCHUNK; c += 1024) load_lds16(wg + c * 8, wlds + c * 8);
      __syncthreads();  // drains vmcnt

      f32x4 acc[4];
#pragma unroll
      for (int n = 0; n < 4; ++n) acc[n] = (f32x4){0.f, 0.f, 0.f, 0.f};

      const u16* hp = hi + (band * 16 + l15) * ASTR + q * 8;
      const u16* lp = lo + (band * 16 + l15) * ASTR + q * 8;
      const u16* bp = wlds + (ct0 * 16 + l15) * WSTR + q * 8;
#pragma unroll
      for (int ks = 0; ks < 7; ++ks) {
        s16x8 ah = *(const s16x8*)(hp + ks * 32);
        s16x8 al = *(const s16x8*)(lp + ks * 32);
#pragma unroll
        for (int n = 0; n < 4; ++n) {
          if (n < cnt) {
            s16x8 b = *(const s16x8*)(bp + n * 16 * WSTR + ks * 32);
            acc[n] = __builtin_amdgcn_mfma_f32_16x16x32_bf16(ah, b, acc[n], 0, 0, 0);
            acc[n] = __builtin_amdgcn_mfma_f32_16x16x32_bf16(al, b, acc[n], 0, 0, 0);
          }
        }
      }
      __syncthreads();  // ALL waves' A/B reads done before in-place writes

      // epilogue: bias + relu + hi/lo split, in-place (per-wave disjoint)
#pragma unroll
      for (int n = 0; n < 4; ++n) {
        if (n < cnt) {
          int ctile = (ct0 + n) * 16;
#pragma unroll
          for (int r = 0; r < 4; ++r) {
            int rr = (mode == 0) ? (q * 4 + r) : l15;
            int cc = (mode == 0) ? l15 : (q * 4 + r);
            int row = band * 16 + rr, col = ctile + cc;
            float v = acc[n][r] + ((col < HID) ? ldf(b_hid, l * HID + col, isbf) : 0.f);
            v = fmaxf(v, 0.f);
            u16 h = f2bf(v);
            hi[row * ASTR + col] = h;
            lo[row * ASTR + col] = f2bf(v - bf2f(h));
          }
        }
      }
    }

    __syncthreads();
    // Output layer: 16 threads per row, 13 cols each
    {
      int m = tid >> 4, c = tid & 15;
      float s = 0.f;
      for (int j = c * 13; j < c * 13 + 13 && j < HID; ++j)
        s += (bf2f(hi[m * ASTR + j]) + bf2f(lo[m * ASTR + j])) * ldf(w_out, j, isbf);
      s += __shfl_down(s, 8);
      s += __shfl_down(s, 4);
      s += __shfl_down(s, 2);
      s += __shfl_down(s, 1);
      if (c == 0) {
        float logit = s + ldf(b_out, 0, isbf);
        float o = 1.f / (1.f + __expf(-logit));
        if (isbf) ((u16*)out)[nb + m] = f2bf(o);
        else ((float*)out)[nb + m] = o;
      }
    }
  } else {
    // ---- VALU fallback (never observed; defensive) ----
    float(*fA)[201] = (float(*)[201])smem;
    float(*fB)[201] = (float(*)[201])(smem + MT * 201 * 4);
    for (int i = tid; i < MT * HID; i += 1024) {
      int mm = i / HID, ff = i - mm * HID;
      float v = h0s[mm] * ldf(w_in, ff, isbf) + ldf(b_in, ff, isbf);
      fA[mm][ff] = v > 0.f ? v : 0.f;
    }
    __syncthreads();
    const int m = tid >> 4, c = tid & 15;
    float(*ain)[201] = fA;
    float(*aout)[201] = fB;
    for (int l = 0; l < 6; ++l) {
      float acc[13];
#pragma unroll
      for (int jj = 0; jj < 13; ++jj) {
        int j = c * 13 + jj;
        acc[jj] = (j < HID) ? ldf(b_hid, l * HID + j, isbf) : 0.f;
      }
      const float* wl = g_wf + l * HID * HID;
      for (int k = 0; k < HID; ++k) {
        float a = ain[m][k];
        const float* wr = wl + k * HID;
#pragma unroll
        for (int jj = 0; jj < 13; ++jj) {
          int j = c * 13 + jj;
          if (j < HID) acc[jj] = fmaf(a, wr[j], acc[jj]);
        }
      }
      __syncthreads();
#pragma unroll
      for (int jj = 0; jj < 13; ++jj) {
        int j = c * 13 + jj;
        if (j < HID) aout[m][j] = fmaxf(acc[jj], 0.f);
      }
      float(*tsw)[201] = ain; ain = aout; aout = tsw;
      __syncthreads();
    }
    float s = 0.f;
    for (int j = c * 13; j < c * 13 + 13 && j < HID; ++j)
      s += ain[m][j] * ldf(w_out, j, isbf);
    s += __shfl_down(s, 8);
    s += __shfl_down(s, 4);
    s += __shfl_down(s, 2);
    s += __shfl_down(s, 1);
    if (c == 0) {
      float logit = s + ldf(b_out, 0, isbf);
      float o = 1.f / (1.f + __expf(-logit));
      if (isbf) ((u16*)out)[nb + m] = f2bf(o);
      else ((float*)out)[nb + m] = o;
    }
  }
}

extern "C" void kernel_launch(void* const* d_in, const int* in_sizes, int n_in,
                              void* d_out, int out_size, void* d_ws, size_t ws_size,
                              hipStream_t stream) {
  const void* x      = d_in[0];
  const int* ei      = (const int*)d_in[1];
  const void* w_rel  = d_in[2];
  const void* b_rel  = d_in[3];
  const void* w_root = d_in[4];
  const void* w_in   = d_in[5];
  const void* b_in   = d_in[6];
  const void* w_hid  = d_in[7];
  const void* b_hid  = d_in[8];
  const void* w_out  = d_in[9];
  const void* b_out  = d_in[10];
  (void)d_ws; (void)ws_size; (void)in_sizes; (void)n_in; (void)out_size;

  sniff_kernel<<<1, 64, 0, stream>>>((const u32*)x);
  prep_kernel<<<(NREP * N_NODES + 255) / 256, 256, 0, stream>>>(w_hid);
  scatter_kernel<<<N_EDGES / 4 / 256, 256, 0, stream>>>(ei, x);
  mlp_kernel<<<N_NODES / MT, 1024, LDS_TOTAL, stream>>>(
      x, w_rel, b_rel, w_root, w_in, b_in, b_hid, w_out, b_out, d_out);
}

// Round 7
// 766.215 us; speedup vs baseline: 10.9056x; 1.2041x over previous
//
#include <hip/hip_runtime.h>

#define N_NODES 200000
#define N_EDGES 6400000
#define HID 200
#define NREP 4                    // scatter accumulator replicas
#define MT 128                    // nodes per block
#define ASTR 232                  // act row stride (fp16 elems): 464 B, 116 words %32=20 -> conflict-free-ish
#define APLANE (MT * ASTR)        // 29696 elems = 59392 B
#define WSTR 232
#define WROWS 224
#define WELEMS (WROWS * WSTR)     // 51968 elems = 103936 B (fp16)
#define WCHUNK (WELEMS / 8)       // 6496 16-B chunks

// LDS map: act [0, 59392) ; wlds [59392, 163328) ; h0s aliased at [59392, 59904)
// (h0s dead once first weight stage begins). Total 163,328 <= 163,840.
#define LDS_W 59392
#define LDS_TOTAL 163328

typedef float f32x4 __attribute__((ext_vector_type(4)));
typedef _Float16 f16x8 __attribute__((ext_vector_type(8)));
typedef unsigned short u16;
typedef unsigned int u32;

__device__ __align__(16) float g_agg[NREP * N_NODES];
__device__ __align__(16) float g_wf[6 * HID * HID];      // fp32 [l][k][f] (VALU fallback)
__device__ __align__(16) _Float16 g_wph[6 * WELEMS];     // fp16 W^T padded [l][n][k] (MFMA)
__device__ int g_isbf;

__device__ __forceinline__ float bf2f(u16 u) {
  union { u32 i; float f; } v; v.i = ((u32)u) << 16; return v.f;
}
__device__ __forceinline__ u16 f2bf(float f) {  // RNE
  u32 i = __float_as_uint(f);
  return (u16)((i + 0x7FFFu + ((i >> 16) & 1u)) >> 16);
}
__device__ __forceinline__ float ldf(const void* p, int i, int isbf) {
  return isbf ? bf2f(((const u16*)p)[i]) : ((const float*)p)[i];
}
__device__ __forceinline__ void load_lds16(const void* g, void* l) {
  __builtin_amdgcn_global_load_lds(
      (const __attribute__((address_space(1))) u32*)g,
      (__attribute__((address_space(3))) u32*)l, 16, 0, 0);
}

// ---- rank-2 MFMA layout self-test (fp16), reference folded at compile time ----
constexpr int tf1(int m) { return (m & 3) + 1; }
constexpr int tf2(int m) { return ((m >> 2) & 3) + 2; }
constexpr int tg1(int k) { return (k & 7) + 1; }
constexpr int tg2(int k) { return ((k >> 3) & 3) + 1; }
constexpr int tu1(int k) { return ((k * 3) & 7) + 1; }
constexpr int tu2(int k) { return ((k >> 2) & 3) + 2; }
constexpr int tw1(int n) { return ((n * 5) & 7) + 1; }
constexpr int tw2(int n) { return ((n >> 2) & 3) + 1; }
constexpr int calcS(int i, int j) {
  int s = 0;
  for (int k = 0; k < 32; ++k)
    s += (i ? tg2(k) : tg1(k)) * (j ? tu2(k) : tu1(k));
  return s;
}
__device__ __forceinline__ float refD(int m, int n) {
  constexpr int S11 = calcS(0, 0), S12 = calcS(0, 1), S21 = calcS(1, 0), S22 = calcS(1, 1);
  return (float)(tf1(m) * tw1(n) * S11 + tf1(m) * tw2(n) * S12 +
                 tf2(m) * tw1(n) * S21 + tf2(m) * tw2(n) * S22);
}
__device__ int mfma_selftest(int l15, int q) {
  f16x8 av, bv;
#pragma unroll
  for (int j = 0; j < 8; ++j) {
    int k = q * 8 + j;                 // the hot loop's believed k-map
    av[j] = (_Float16)(float)(tf1(l15) * tg1(k) + tf2(l15) * tg2(k));
    bv[j] = (_Float16)(float)(tu1(k) * tw1(l15) + tu2(k) * tw2(l15));
  }
  f32x4 d = __builtin_amdgcn_mfma_f32_16x16x32_f16(av, bv, (f32x4){0.f, 0.f, 0.f, 0.f}, 0, 0, 0);
  bool ok0 = true, ok1 = true;
#pragma unroll
  for (int r = 0; r < 4; ++r) {
    ok0 = ok0 && (d[r] == refD(q * 4 + r, l15));
    ok1 = ok1 && (d[r] == refD(l15, q * 4 + r));
  }
  return __all(ok0) ? 0 : (__all(ok1) ? 1 : 2);
}

// ---- K0: dtype sniff ----
__global__ void sniff_kernel(const u32* __restrict__ xw) {
  int i = threadIdx.x;  // 64 threads
  u32 e = (xw[i] >> 7) & 0xFFu;
  unsigned long long b = __ballot(e >= 110u && e <= 135u);
  if (i == 0) g_isbf = (__popcll(b) >= 48) ? 1 : 0;
}

// ---- K1: zero replicas + both weight forms (fp16 exact from bf16) ----
__global__ void prep_kernel(const void* __restrict__ w_hid) {
  int t = blockIdx.x * blockDim.x + threadIdx.x;
  int isbf = g_isbf;
  if (t < NREP * N_NODES) g_agg[t] = 0.f;
  if (t < 6 * HID * HID) g_wf[t] = ldf(w_hid, t, isbf);
  if (t < 6 * WELEMS) {
    int l = t / WELEMS;
    int r = t - l * WELEMS;
    int n = r / WSTR;
    int k = r - n * WSTR;
    float v = 0.f;
    if (n < HID && k < HID) v = ldf(w_hid, (l * HID + k) * HID + n, isbf);
    g_wph[t] = (_Float16)v;
  }
}

// ---- K2: edge scatter-add into replica blockIdx&3 (unchanged from R6) ----
__global__ void scatter_kernel(const int* __restrict__ ei, const void* __restrict__ x) {
  int t = blockIdx.x * blockDim.x + threadIdx.x;
  int e = t * 4;
  int isbf = g_isbf;
  float* agg = g_agg + (size_t)(blockIdx.x & (NREP - 1)) * N_NODES;
  bool is64 = ((ei[1] | ei[3] | ei[5] | ei[7]) == 0);
  int s0, s1, s2, s3, d0, d1, d2, d3;
  if (is64) {
    int4 a = *(const int4*)(ei + 2 * e);
    int4 b = *(const int4*)(ei + 2 * e + 4);
    int4 c = *(const int4*)(ei + 2 * N_EDGES + 2 * e);
    int4 d = *(const int4*)(ei + 2 * N_EDGES + 2 * e + 4);
    s0 = a.x; s1 = a.z; s2 = b.x; s3 = b.z;
    d0 = c.x; d1 = c.z; d2 = d.x; d3 = d.z;
  } else {
    int4 s4 = *(const int4*)(ei + e);
    int4 d4 = *(const int4*)(ei + N_EDGES + e);
    s0 = s4.x; s1 = s4.y; s2 = s4.z; s3 = s4.w;
    d0 = d4.x; d1 = d4.y; d2 = d4.z; d3 = d4.w;
  }
  atomicAdd(&agg[d0], ldf(x, s0, isbf));
  atomicAdd(&agg[d1], ldf(x, s1, isbf));
  atomicAdd(&agg[d2], ldf(x, s2, isbf));
  atomicAdd(&agg[d3], ldf(x, s3, isbf));
}

// ---- K3: fused MLP, 1024 thr / 16 waves, MT=128, single fp16 act plane ----
__global__ __launch_bounds__(1024) void mlp_kernel(
    const void* __restrict__ x,
    const void* __restrict__ w_rel, const void* __restrict__ b_rel, const void* __restrict__ w_root,
    const void* __restrict__ w_in, const void* __restrict__ b_in,
    const void* __restrict__ b_hid, const void* __restrict__ w_out, const void* __restrict__ b_out,
    void* __restrict__ out) {
  extern __shared__ char smem[];
  _Float16* act = (_Float16*)smem;
  _Float16* wlds = (_Float16*)(smem + LDS_W);
  float* h0s = (float*)(smem + LDS_W);  // aliased: dead once first stage begins

  const int tid = threadIdx.x;
  const int nb = blockIdx.x * MT;
  const int isbf = g_isbf;
  const int lane = tid & 63;
  const int wv = tid >> 6;
  const int l15 = lane & 15;
  const int q = lane >> 4;

  const int mode = mfma_selftest(l15, q);

  // GraphConv h0 (replica-summed), guarded for tail block
  if (tid < MT) {
    int node = nb + tid;
    float v = 0.f;
    if (node < N_NODES) {
      float a = g_agg[node] + g_agg[N_NODES + node] +
                g_agg[2 * N_NODES + node] + g_agg[3 * N_NODES + node];
      v = a * ldf(w_rel, 0, isbf) + ldf(b_rel, 0, isbf) +
          ldf(x, node, isbf) * ldf(w_root, 0, isbf);
    }
    h0s[tid] = v;
  }
  __syncthreads();

  if (mode < 2) {
    // Input layer: act[m][j] = relu(h0[m]*w_in[j]+b_in[j]); pad cols zeroed
    for (int idx = tid; idx < APLANE; idx += 1024) {
      int m = idx / ASTR, j = idx - m * ASTR;
      float v = 0.f;
      if (j < HID) {
        v = h0s[m] * ldf(w_in, j, isbf) + ldf(b_in, j, isbf);
        v = fmaxf(v, 0.f);
      }
      act[idx] = (_Float16)v;
    }

    const int band = wv >> 2;                    // 4 bands x 32 rows (Mt=2)
    const int g = wv & 3;                        // col groups: tiles 4/4/3/3
    const int ct0 = (g < 2) ? g * 4 : 8 + (g - 2) * 3;
    const int cnt = (g < 2) ? 4 : 3;

    for (int l = 0; l < 6; ++l) {
      __syncthreads();  // input-layer/epilogue writes + prior wlds reads done
      const _Float16* wg = g_wph + l * WELEMS;
      for (int c = tid; c < WCHUNK; c += 1024) load_lds16(wg + c * 8, wlds + c * 8);
      __syncthreads();  // drains vmcnt

      f32x4 acc[2][4];
#pragma unroll
      for (int h = 0; h < 2; ++h)
#pragma unroll
        for (int n = 0; n < 4; ++n) acc[h][n] = (f32x4){0.f, 0.f, 0.f, 0.f};

      const _Float16* ap = act + (band * 32 + l15) * ASTR + q * 8;
      const _Float16* bp = wlds + (ct0 * 16 + l15) * WSTR + q * 8;
#pragma unroll
      for (int ks = 0; ks < 7; ++ks) {
        f16x8 a0 = *(const f16x8*)(ap + ks * 32);
        f16x8 a1 = *(const f16x8*)(ap + 16 * ASTR + ks * 32);
#pragma unroll
        for (int n = 0; n < 4; ++n) {
          if (n < cnt) {
            f16x8 b = *(const f16x8*)(bp + n * 16 * WSTR + ks * 32);
            acc[0][n] = __builtin_amdgcn_mfma_f32_16x16x32_f16(a0, b, acc[0][n], 0, 0, 0);
            acc[1][n] = __builtin_amdgcn_mfma_f32_16x16x32_f16(a1, b, acc[1][n], 0, 0, 0);
          }
        }
      }
      __syncthreads();  // all A/B reads done before in-place writes

      // epilogue: bias + relu, in-place fp16 (per-wave disjoint region)
#pragma unroll
      for (int n = 0; n < 4; ++n) {
        if (n < cnt) {
          int ctile = (ct0 + n) * 16;
#pragma unroll
          for (int h = 0; h < 2; ++h) {
#pragma unroll
            for (int r = 0; r < 4; ++r) {
              int rr = (mode == 0) ? (q * 4 + r) : l15;
              int cc = (mode == 0) ? l15 : (q * 4 + r);
              int row = band * 32 + h * 16 + rr, col = ctile + cc;
              float v = acc[h][n][r] + ((col < HID) ? ldf(b_hid, l * HID + col, isbf) : 0.f);
              act[row * ASTR + col] = (_Float16)fmaxf(v, 0.f);
            }
          }
        }
      }
    }

    __syncthreads();
    // Output layer: 8 threads per row, 25 cols each
    {
      int m = tid >> 3, c = tid & 7;
      const _Float16* ar = act + m * ASTR;
      float s = 0.f;
#pragma unroll
      for (int j = c * 25; j < c * 25 + 25; ++j)
        s += (float)ar[j] * ldf(w_out, j, isbf);
      s += __shfl_down(s, 4);
      s += __shfl_down(s, 2);
      s += __shfl_down(s, 1);
      int node = nb + m;
      if (c == 0 && node < N_NODES) {
        float logit = s + ldf(b_out, 0, isbf);
        float o = 1.f / (1.f + __expf(-logit));
        if (isbf) ((u16*)out)[node] = f2bf(o);
        else ((float*)out)[node] = o;
      }
    }
  } else {
    // ---- VALU fallback (defensive; 2 passes of 64 nodes) ----
    float(*fA)[201] = (float(*)[201])smem;                       // 51,456 B in act region
    float(*fB)[201] = (float(*)[201])(smem + LDS_W + 512);       // after h0s
    for (int p = 0; p < 2; ++p) {
      __syncthreads();
      for (int i = tid; i < 64 * HID; i += 1024) {
        int mm = i / HID, ff = i - mm * HID;
        float v = h0s[p * 64 + mm] * ldf(w_in, ff, isbf) + ldf(b_in, ff, isbf);
        fA[mm][ff] = v > 0.f ? v : 0.f;
      }
      __syncthreads();
      const int m = tid >> 4, c = tid & 15;
      float(*ain)[201] = fA;
      float(*aout)[201] = fB;
      for (int l = 0; l < 6; ++l) {
        float acc[13];
#pragma unroll
        for (int jj = 0; jj < 13; ++jj) {
          int j = c * 13 + jj;
          acc[jj] = (j < HID) ? ldf(b_hid, l * HID + j, isbf) : 0.f;
        }
        const float* wl = g_wf + l * HID * HID;
        for (int k = 0; k < HID; ++k) {
          float a = ain[m][k];
          const float* wr = wl + k * HID;
#pragma unroll
          for (int jj = 0; jj < 13; ++jj) {
            int j = c * 13 + jj;
            if (j < HID) acc[jj] = fmaf(a, wr[j], acc[jj]);
          }
        }
        __syncthreads();
#pragma unroll
        for (int jj = 0; jj < 13; ++jj) {
          int j = c * 13 + jj;
          if (j < HID) aout[m][j] = fmaxf(acc[jj], 0.f);
        }
        float(*tsw)[201] = ain; ain = aout; aout = tsw;
        __syncthreads();
      }
      float s = 0.f;
      for (int j = c * 13; j < c * 13 + 13 && j < HID; ++j)
        s += ain[m][j] * ldf(w_out, j, isbf);
      s += __shfl_down(s, 8);
      s += __shfl_down(s, 4);
      s += __shfl_down(s, 2);
      s += __shfl_down(s, 1);
      int node = nb + p * 64 + m;
      if (c == 0 && node < N_NODES) {
        float logit = s + ldf(b_out, 0, isbf);
        float o = 1.f / (1.f + __expf(-logit));
        if (isbf) ((u16*)out)[node] = f2bf(o);
        else ((float*)out)[node] = o;
      }
    }
  }
}

extern "C" void kernel_launch(void* const* d_in, const int* in_sizes, int n_in,
                              void* d_out, int out_size, void* d_ws, size_t ws_size,
                              hipStream_t stream) {
  const void* x      = d_in[0];
  const int* ei      = (const int*)d_in[1];
  const void* w_rel  = d_in[2];
  const void* b_rel  = d_in[3];
  const void* w_root = d_in[4];
  const void* w_in   = d_in[5];
  const void* b_in   = d_in[6];
  const void* w_hid  = d_in[7];
  const void* b_hid  = d_in[8];
  const void* w_out  = d_in[9];
  const void* b_out  = d_in[10];
  (void)d_ws; (void)ws_size; (void)in_sizes; (void)n_in; (void)out_size;

  sniff_kernel<<<1, 64, 0, stream>>>((const u32*)x);
  prep_kernel<<<(NREP * N_NODES + 255) / 256, 256, 0, stream>>>(w_hid);
  scatter_kernel<<<N_EDGES / 4 / 256, 256, 0, stream>>>(ei, x);
  mlp_kernel<<<(N_NODES + MT - 1) / MT, 1024, LDS_TOTAL, stream>>>(
      x, w_rel, b_rel, w_root, w_in, b_in, b_hid, w_out, b_out, d_out);
}